// Round 1
// baseline (81.823 us; speedup 1.0000x reference)
//
#include <hip/hip_runtime.h>
#include <hip/hip_fp16.h>

#define HH 64
#define WW 96
#define DD 64
#define VV 4
#define CC 16
#define HW (HH*WW)
#define EPSF 1e-8f

// depths per thread / block size for the main kernel
#define DPT 4
#define MBLK 128

typedef _Float16 half2_t __attribute__((ext_vector_type(2)));

#if defined(__has_builtin)
#if __has_builtin(__builtin_amdgcn_fdot2)
#define HAVE_FDOT2 1
#endif
#endif

__device__ __forceinline__ float fdot2_acc(half2_t a, half2_t b, float c) {
#ifdef HAVE_FDOT2
    return __builtin_amdgcn_fdot2(a, b, c, false);
#else
    return c + (float)a.x * (float)b.x + (float)a.y * (float)b.y;
#endif
}

// ---------------------------------------------------------------------------
// Pack kernel: src (V,C,HW) fp32 -> srcT (V,HW,C) fp16
//              cur (C,HW)  fp32 -> curT (HW,C)   fp16
// One thread per pixel: channel reads coalesced across lanes, 32B packed write.
// ---------------------------------------------------------------------------
__global__ __launch_bounds__(256) void cv_pack_kernel(
    const float* __restrict__ src, const float* __restrict__ cur,
    __half* __restrict__ srcT, __half* __restrict__ curT)
{
    int tid = blockIdx.x * blockDim.x + threadIdx.x;
    if (tid < VV * HW) {
        int v  = tid / HW;
        int hw = tid - v * HW;
        unsigned short pk[CC];
        #pragma unroll
        for (int c = 0; c < CC; ++c) {
            float f = src[(size_t)v * CC * HW + c * HW + hw];
            pk[c] = __half_as_ushort(__float2half(f));
        }
        uint4* dst = (uint4*)(srcT + (size_t)tid * CC);
        dst[0] = *(uint4*)&pk[0];
        dst[1] = *(uint4*)&pk[8];
    } else {
        int hw = tid - VV * HW;
        if (hw < HW) {
            unsigned short pk[CC];
            #pragma unroll
            for (int c = 0; c < CC; ++c) {
                float f = cur[c * HW + hw];
                pk[c] = __half_as_ushort(__float2half(f));
            }
            uint4* dst = (uint4*)(curT + (size_t)hw * CC);
            dst[0] = *(uint4*)&pk[0];
            dst[1] = *(uint4*)&pk[8];
        }
    }
}

// 32B fp16 tap: 8 x v_dot2_f32_f16 against fp16 cf, fp32 accumulate
__device__ __forceinline__ float tap_dot16(const __half* __restrict__ p,
                                           const half2_t* __restrict__ cf2)
{
    half2_t hv[8];
    const uint4* q = (const uint4*)p;
    *(uint4*)&hv[0] = q[0];
    *(uint4*)&hv[4] = q[1];
    float s = 0.f;
    #pragma unroll
    for (int i = 0; i < 8; ++i)
        s = fdot2_acc(hv[i], cf2[i], s);
    return s;
}

// ---------------------------------------------------------------------------
// Main fused kernel, v2: DPT depths per thread.
//  - ray / P.r dots / cf2 load / depth setup amortized across DPT depths
//  - all divides -> v_rcp_f32 (1 ulp; negligible vs fp16-dot rounding)
//  - branchless view body: tap loads unconditional, (cz>0) applied as select
//    (clamped indices are always in-range, so loads are always safe; any NaN
//    weights from degenerate iz are discarded by the select)
// Grid: (DD/DPT) d-groups x (HW/MBLK) blocks = 16*48 = 768 blocks = 3/CU.
// ---------------------------------------------------------------------------
__global__ __launch_bounds__(MBLK) void cost_volume_f16_kernel(
    const __half* __restrict__ curT,
    const __half* __restrict__ srcT,
    const float* __restrict__ extr,   // (V,4,4)
    const float* __restrict__ Ks,     // (V,4,4)
    const float* __restrict__ invK,   // (4,4)
    const float* __restrict__ min_d,
    const float* __restrict__ max_d,
    float* __restrict__ out)          // (D,HW)
{
    __shared__ float P_s[VV * 12];
    {
        int t = threadIdx.x;
        if (t < VV * 12) {
            int v   = t / 12;
            int r   = (t % 12) / 4;
            int col = t % 4;
            float s = 0.f;
            #pragma unroll
            for (int k = 0; k < 4; ++k)
                s += Ks[v * 16 + r * 4 + k] * extr[v * 16 + k * 4 + col];
            P_s[t] = s;
        }
    }
    __syncthreads();

    const int dg = blockIdx.x / (HW / MBLK);                       // 0..15
    const int hw = (blockIdx.x % (HW / MBLK)) * MBLK + threadIdx.x;
    const int h  = hw / WW;
    const int w  = hw - h * WW;

    float px = (float)w + 0.5f, py = (float)h + 0.5f;
    float rx = invK[0] * px + invK[1] * py + invK[2];
    float ry = invK[4] * px + invK[5] * py + invK[6];
    float rz = invK[8] * px + invK[9] * py + invK[10];

    float inv_min = __builtin_amdgcn_rcpf(min_d[0]);
    float inv_max = __builtin_amdgcn_rcpf(max_d[0]);
    float dmm = inv_max - inv_min;

    float dep[DPT];
    #pragma unroll
    for (int i = 0; i < DPT; ++i) {
        float fd = (float)(dg * DPT + i) * (1.f / (float)(DD - 1));
        dep[i] = __builtin_amdgcn_rcpf(inv_min + dmm * fd);
    }

    half2_t cf2[8];
    {
        const uint4* p = (const uint4*)(curT + (size_t)hw * CC);
        *(uint4*)&cf2[0] = p[0];
        *(uint4*)&cf2[4] = p[1];
    }

    float acc[DPT];
    #pragma unroll
    for (int i = 0; i < DPT; ++i) acc[i] = 0.f;

    #pragma unroll
    for (int v = 0; v < VV; ++v) {
        const float* P = &P_s[v * 12];
        float a = P[0] * rx + P[1] * ry + P[2]  * rz;
        float b = P[4] * rx + P[5] * ry + P[6]  * rz;
        float c = P[8] * rx + P[9] * ry + P[10] * rz;
        const __half* base = srcT + (size_t)v * HW * CC;

        #pragma unroll
        for (int i = 0; i < DPT; ++i) {
            float cz = dep[i] * c + P[11];
            float cx = dep[i] * a + P[3];
            float cy = dep[i] * b + P[7];
            float iz = __builtin_amdgcn_rcpf(cz + EPSF);
            float x = cx * iz - 0.5f;
            float y = cy * iz - 0.5f;
            float x0f = floorf(x), y0f = floorf(y);
            float fx = x - x0f, fy = y - y0f;
            float x1f = x0f + 1.f, y1f = y0f + 1.f;
            int ix0 = (int)fminf(fmaxf(x0f, 0.f), (float)(WW - 1));
            int ix1 = (int)fminf(fmaxf(x1f, 0.f), (float)(WW - 1));
            int iy0 = (int)fminf(fmaxf(y0f, 0.f), (float)(HH - 1));
            int iy1 = (int)fminf(fmaxf(y1f, 0.f), (float)(HH - 1));
            bool vx0 = (x0f >= 0.f) && (x0f < (float)WW);
            bool vx1 = (x1f >= 0.f) && (x1f < (float)WW);
            bool vy0 = (y0f >= 0.f) && (y0f < (float)HH);
            bool vy1 = (y1f >= 0.f) && (y1f < (float)HH);
            float w00 = (vx0 && vy0) ? (1.f - fx) * (1.f - fy) : 0.f;
            float w01 = (vx1 && vy0) ? fx * (1.f - fy) : 0.f;
            float w10 = (vx0 && vy1) ? (1.f - fx) * fy : 0.f;
            float w11 = (vx1 && vy1) ? fx * fy : 0.f;

            float d00 = tap_dot16(base + (size_t)(iy0 * WW + ix0) * CC, cf2);
            float d01 = tap_dot16(base + (size_t)(iy0 * WW + ix1) * CC, cf2);
            float d10 = tap_dot16(base + (size_t)(iy1 * WW + ix0) * CC, cf2);
            float d11 = tap_dot16(base + (size_t)(iy1 * WW + ix1) * CC, cf2);

            float vacc = w00 * d00 + w01 * d01 + w10 * d10 + w11 * d11;
            acc[i] += (cz > 0.f) ? vacc : 0.f;
        }
    }

    #pragma unroll
    for (int i = 0; i < DPT; ++i)
        out[(size_t)(dg * DPT + i) * HW + hw] = acc[i];
}

// ---------------------------------------------------------------------------
// Fallback (no workspace): original-layout fp32 gather.
// ---------------------------------------------------------------------------
__global__ __launch_bounds__(256) void cost_volume_fallback_kernel(
    const float* __restrict__ curF,   // (C,HW)
    const float* __restrict__ srcF,   // (V,C,HW)
    const float* __restrict__ extr,
    const float* __restrict__ Ks,
    const float* __restrict__ invK,
    const float* __restrict__ min_d,
    const float* __restrict__ max_d,
    float* __restrict__ out)
{
    __shared__ float P_s[VV * 12];
    {
        int t = threadIdx.x;
        if (t < VV * 12) {
            int v   = t / 12;
            int r   = (t % 12) / 4;
            int col = t % 4;
            float s = 0.f;
            #pragma unroll
            for (int k = 0; k < 4; ++k)
                s += Ks[v * 16 + r * 4 + k] * extr[v * 16 + k * 4 + col];
            P_s[t] = s;
        }
    }
    __syncthreads();

    int tid = blockIdx.x * blockDim.x + threadIdx.x;
    if (tid >= DD * HW) return;
    int d  = tid / HW;
    int hw = tid - d * HW;
    int h  = hw / WW;
    int w  = hw - h * WW;

    float px = (float)w + 0.5f, py = (float)h + 0.5f;
    float rx = invK[0] * px + invK[1] * py + invK[2];
    float ry = invK[4] * px + invK[5] * py + invK[6];
    float rz = invK[8] * px + invK[9] * py + invK[10];

    float inv_min = 1.f / min_d[0];
    float inv_max = 1.f / max_d[0];
    float depth   = 1.f / (inv_min + (inv_max - inv_min) * ((float)d / (float)(DD - 1)));

    float cf[CC];
    #pragma unroll
    for (int c = 0; c < CC; ++c) cf[c] = curF[c * HW + hw];

    float acc = 0.f;
    #pragma unroll
    for (int v = 0; v < VV; ++v) {
        const float* P = &P_s[v * 12];
        float cx = depth * (P[0] * rx + P[1] * ry + P[2]  * rz) + P[3];
        float cy = depth * (P[4] * rx + P[5] * ry + P[6]  * rz) + P[7];
        float cz = depth * (P[8] * rx + P[9] * ry + P[10] * rz) + P[11];
        if (cz > 0.f) {
            float iz = 1.f / (cz + EPSF);
            float x = cx * iz - 0.5f;
            float y = cy * iz - 0.5f;
            float x0f = floorf(x), y0f = floorf(y);
            float fx = x - x0f, fy = y - y0f;
            float x1f = x0f + 1.f, y1f = y0f + 1.f;
            int ix0 = (int)fminf(fmaxf(x0f, 0.f), (float)(WW - 1));
            int ix1 = (int)fminf(fmaxf(x1f, 0.f), (float)(WW - 1));
            int iy0 = (int)fminf(fmaxf(y0f, 0.f), (float)(HH - 1));
            int iy1 = (int)fminf(fmaxf(y1f, 0.f), (float)(HH - 1));
            bool vx0 = (x0f >= 0.f) && (x0f < (float)WW);
            bool vx1 = (x1f >= 0.f) && (x1f < (float)WW);
            bool vy0 = (y0f >= 0.f) && (y0f < (float)HH);
            bool vy1 = (y1f >= 0.f) && (y1f < (float)HH);
            float w00 = (vx0 && vy0) ? (1.f - fx) * (1.f - fy) : 0.f;
            float w01 = (vx1 && vy0) ? fx * (1.f - fy) : 0.f;
            float w10 = (vx0 && vy1) ? (1.f - fx) * fy : 0.f;
            float w11 = (vx1 && vy1) ? fx * fy : 0.f;

            float d00 = 0.f, d01 = 0.f, d10 = 0.f, d11 = 0.f;
            int b = v * CC * HW;
            int i00 = iy0 * WW + ix0, i01 = iy0 * WW + ix1;
            int i10 = iy1 * WW + ix0, i11 = iy1 * WW + ix1;
            #pragma unroll
            for (int c = 0; c < CC; ++c) {
                const float* fc = srcF + b + c * HW;
                d00 += fc[i00] * cf[c];
                d01 += fc[i01] * cf[c];
                d10 += fc[i10] * cf[c];
                d11 += fc[i11] * cf[c];
            }
            acc += w00 * d00 + w01 * d01 + w10 * d10 + w11 * d11;
        }
    }
    out[tid] = acc;
}

extern "C" void kernel_launch(void* const* d_in, const int* in_sizes, int n_in,
                              void* d_out, int out_size, void* d_ws, size_t ws_size,
                              hipStream_t stream) {
    const float* cur  = (const float*)d_in[0];
    const float* src  = (const float*)d_in[1];
    const float* extr = (const float*)d_in[2];
    const float* Ks   = (const float*)d_in[3];
    const float* invK = (const float*)d_in[4];
    const float* mind = (const float*)d_in[5];
    const float* maxd = (const float*)d_in[6];
    float* out = (float*)d_out;

    const size_t need = (size_t)(VV * HW * CC + HW * CC) * sizeof(__half);
    const int n_out  = DD * HW;

    if (ws_size >= need) {
        __half* srcT = (__half*)d_ws;
        __half* curT = srcT + (size_t)VV * HW * CC;
        const int total = VV * HW + HW;
        cv_pack_kernel<<<(total + 255) / 256, 256, 0, stream>>>(src, cur, srcT, curT);
        const int mblocks = (DD / DPT) * (HW / MBLK);   // 16 * 48 = 768
        cost_volume_f16_kernel<<<mblocks, MBLK, 0, stream>>>(
            curT, srcT, extr, Ks, invK, mind, maxd, out);
    } else {
        const int blocks = (n_out + 255) / 256;
        cost_volume_fallback_kernel<<<blocks, 256, 0, stream>>>(
            cur, src, extr, Ks, invK, mind, maxd, out);
    }
}

// Round 2
// 79.117 us; speedup vs baseline: 1.0342x; 1.0342x over previous
//
#include <hip/hip_runtime.h>
#include <hip/hip_fp16.h>

#define HH 64
#define WW 96
#define DD 64
#define VV 4
#define CC 16
#define HW (HH*WW)
#define EPSF 1e-8f

// main kernel: 1 wave (64 lanes) = 64 depth planes of one pixel
#define PIX_PER_BLOCK 4   // 4 waves of 64 = 256 threads

typedef _Float16 half2_t __attribute__((ext_vector_type(2)));

#if defined(__has_builtin)
#if __has_builtin(__builtin_amdgcn_fdot2)
#define HAVE_FDOT2 1
#endif
#endif

__device__ __forceinline__ float fdot2_acc(half2_t a, half2_t b, float c) {
#ifdef HAVE_FDOT2
    return __builtin_amdgcn_fdot2(a, b, c, false);
#else
    return c + (float)a.x * (float)b.x + (float)a.y * (float)b.y;
#endif
}

// ---------------------------------------------------------------------------
// Pack kernel: src (V,C,HW) fp32 -> srcT (V,HW,C) fp16
//              cur (C,HW)  fp32 -> curT (HW,C)   fp16
// One thread per pixel: channel reads coalesced across lanes, 32B packed write.
// ---------------------------------------------------------------------------
__global__ __launch_bounds__(256) void cv_pack_kernel(
    const float* __restrict__ src, const float* __restrict__ cur,
    __half* __restrict__ srcT, __half* __restrict__ curT)
{
    int tid = blockIdx.x * blockDim.x + threadIdx.x;
    if (tid < VV * HW) {
        int v  = tid / HW;
        int hw = tid - v * HW;
        unsigned short pk[CC];
        #pragma unroll
        for (int c = 0; c < CC; ++c) {
            float f = src[(size_t)v * CC * HW + c * HW + hw];
            pk[c] = __half_as_ushort(__float2half(f));
        }
        uint4* dst = (uint4*)(srcT + (size_t)tid * CC);
        dst[0] = *(uint4*)&pk[0];
        dst[1] = *(uint4*)&pk[8];
    } else {
        int hw = tid - VV * HW;
        if (hw < HW) {
            unsigned short pk[CC];
            #pragma unroll
            for (int c = 0; c < CC; ++c) {
                float f = cur[c * HW + hw];
                pk[c] = __half_as_ushort(__float2half(f));
            }
            uint4* dst = (uint4*)(curT + (size_t)hw * CC);
            dst[0] = *(uint4*)&pk[0];
            dst[1] = *(uint4*)&pk[8];
        }
    }
}

// 32B fp16 tap: 8 x v_dot2_f32_f16 against fp16 cf, fp32 accumulate
__device__ __forceinline__ float tap_dot16(const __half* __restrict__ p,
                                           const half2_t* __restrict__ cf2)
{
    half2_t hv[8];
    const uint4* q = (const uint4*)p;
    *(uint4*)&hv[0] = q[0];
    *(uint4*)&hv[4] = q[1];
    float s = 0.f;
    #pragma unroll
    for (int i = 0; i < 8; ++i)
        s = fdot2_acc(hv[i], cf2[i], s);
    return s;
}

// ---------------------------------------------------------------------------
// Main fused kernel, v3: wave-per-pixel, lane = depth plane (DD == 64).
//  - All 64 lanes of a wave sample along ONE pixel's epipolar path: tap
//    addresses across lanes collapse onto few distinct cache lines (vs ~32
//    lines/wave-load with pixel-per-lane mapping) -> TA/L1 line work ~3x down.
//  - cf2 and per-view projection row-dots are wave-uniform (broadcast/SGPR).
//  - Same total thread count as the 76us baseline (393216) -> latency hiding
//    preserved (round-1 lesson: wave pool is load-bearing).
//  - Divides -> v_rcp_f32 (1 ulp, verified passing at same absmax).
// Grid: HW / PIX_PER_BLOCK blocks x 256 threads.
// ---------------------------------------------------------------------------
__global__ __launch_bounds__(256) void cost_volume_f16_kernel(
    const __half* __restrict__ curT,
    const __half* __restrict__ srcT,
    const float* __restrict__ extr,   // (V,4,4)
    const float* __restrict__ Ks,     // (V,4,4)
    const float* __restrict__ invK,   // (4,4)
    const float* __restrict__ min_d,
    const float* __restrict__ max_d,
    float* __restrict__ out)          // (D,HW)
{
    __shared__ float P_s[VV * 12];
    {
        int t = threadIdx.x;
        if (t < VV * 12) {
            int v   = t / 12;
            int r   = (t % 12) / 4;
            int col = t % 4;
            float s = 0.f;
            #pragma unroll
            for (int k = 0; k < 4; ++k)
                s += Ks[v * 16 + r * 4 + k] * extr[v * 16 + k * 4 + col];
            P_s[t] = s;
        }
    }
    __syncthreads();

    const int wv   = threadIdx.x >> 6;          // wave in block: 0..3
    const int lane = threadIdx.x & 63;          // depth plane index
    const int hw   = blockIdx.x * PIX_PER_BLOCK + wv;
    const int h    = hw / WW;
    const int w    = hw - h * WW;
    const int d    = lane;

    // wave-uniform ray
    float px = (float)w + 0.5f, py = (float)h + 0.5f;
    float rx = invK[0] * px + invK[1] * py + invK[2];
    float ry = invK[4] * px + invK[5] * py + invK[6];
    float rz = invK[8] * px + invK[9] * py + invK[10];

    float inv_min = __builtin_amdgcn_rcpf(min_d[0]);
    float inv_max = __builtin_amdgcn_rcpf(max_d[0]);
    float depth = __builtin_amdgcn_rcpf(
        inv_min + (inv_max - inv_min) * ((float)d * (1.f / (float)(DD - 1))));

    // wave-uniform current-pixel feature vector (single broadcast line)
    half2_t cf2[8];
    {
        const uint4* p = (const uint4*)(curT + (size_t)hw * CC);
        *(uint4*)&cf2[0] = p[0];
        *(uint4*)&cf2[4] = p[1];
    }

    float acc = 0.f;
    #pragma unroll
    for (int v = 0; v < VV; ++v) {
        const float* P = &P_s[v * 12];
        // wave-uniform row-dots; per-lane only the depth scaling
        float a = P[0] * rx + P[1] * ry + P[2]  * rz;
        float b = P[4] * rx + P[5] * ry + P[6]  * rz;
        float c = P[8] * rx + P[9] * ry + P[10] * rz;

        float cx = depth * a + P[3];
        float cy = depth * b + P[7];
        float cz = depth * c + P[11];

        float iz = __builtin_amdgcn_rcpf(cz + EPSF);
        float x = cx * iz - 0.5f;
        float y = cy * iz - 0.5f;
        float x0f = floorf(x), y0f = floorf(y);
        float fx = x - x0f, fy = y - y0f;
        float x1f = x0f + 1.f, y1f = y0f + 1.f;
        int ix0 = (int)fminf(fmaxf(x0f, 0.f), (float)(WW - 1));
        int ix1 = (int)fminf(fmaxf(x1f, 0.f), (float)(WW - 1));
        int iy0 = (int)fminf(fmaxf(y0f, 0.f), (float)(HH - 1));
        int iy1 = (int)fminf(fmaxf(y1f, 0.f), (float)(HH - 1));
        bool vx0 = (x0f >= 0.f) && (x0f < (float)WW);
        bool vx1 = (x1f >= 0.f) && (x1f < (float)WW);
        bool vy0 = (y0f >= 0.f) && (y0f < (float)HH);
        bool vy1 = (y1f >= 0.f) && (y1f < (float)HH);
        float w00 = (vx0 && vy0) ? (1.f - fx) * (1.f - fy) : 0.f;
        float w01 = (vx1 && vy0) ? fx * (1.f - fy) : 0.f;
        float w10 = (vx0 && vy1) ? (1.f - fx) * fy : 0.f;
        float w11 = (vx1 && vy1) ? fx * fy : 0.f;

        const __half* base = srcT + (size_t)v * HW * CC;
        float d00 = tap_dot16(base + (size_t)(iy0 * WW + ix0) * CC, cf2);
        float d01 = tap_dot16(base + (size_t)(iy0 * WW + ix1) * CC, cf2);
        float d10 = tap_dot16(base + (size_t)(iy1 * WW + ix0) * CC, cf2);
        float d11 = tap_dot16(base + (size_t)(iy1 * WW + ix1) * CC, cf2);

        float vacc = w00 * d00 + w01 * d01 + w10 * d10 + w11 * d11;
        acc += (cz > 0.f) ? vacc : 0.f;
    }

    out[(size_t)d * HW + hw] = acc;
}

// ---------------------------------------------------------------------------
// Fallback (no workspace): original-layout fp32 gather.
// ---------------------------------------------------------------------------
__global__ __launch_bounds__(256) void cost_volume_fallback_kernel(
    const float* __restrict__ curF,   // (C,HW)
    const float* __restrict__ srcF,   // (V,C,HW)
    const float* __restrict__ extr,
    const float* __restrict__ Ks,
    const float* __restrict__ invK,
    const float* __restrict__ min_d,
    const float* __restrict__ max_d,
    float* __restrict__ out)
{
    __shared__ float P_s[VV * 12];
    {
        int t = threadIdx.x;
        if (t < VV * 12) {
            int v   = t / 12;
            int r   = (t % 12) / 4;
            int col = t % 4;
            float s = 0.f;
            #pragma unroll
            for (int k = 0; k < 4; ++k)
                s += Ks[v * 16 + r * 4 + k] * extr[v * 16 + k * 4 + col];
            P_s[t] = s;
        }
    }
    __syncthreads();

    int tid = blockIdx.x * blockDim.x + threadIdx.x;
    if (tid >= DD * HW) return;
    int d  = tid / HW;
    int hw = tid - d * HW;
    int h  = hw / WW;
    int w  = hw - h * WW;

    float px = (float)w + 0.5f, py = (float)h + 0.5f;
    float rx = invK[0] * px + invK[1] * py + invK[2];
    float ry = invK[4] * px + invK[5] * py + invK[6];
    float rz = invK[8] * px + invK[9] * py + invK[10];

    float inv_min = 1.f / min_d[0];
    float inv_max = 1.f / max_d[0];
    float depth   = 1.f / (inv_min + (inv_max - inv_min) * ((float)d / (float)(DD - 1)));

    float cf[CC];
    #pragma unroll
    for (int c = 0; c < CC; ++c) cf[c] = curF[c * HW + hw];

    float acc = 0.f;
    #pragma unroll
    for (int v = 0; v < VV; ++v) {
        const float* P = &P_s[v * 12];
        float cx = depth * (P[0] * rx + P[1] * ry + P[2]  * rz) + P[3];
        float cy = depth * (P[4] * rx + P[5] * ry + P[6]  * rz) + P[7];
        float cz = depth * (P[8] * rx + P[9] * ry + P[10] * rz) + P[11];
        if (cz > 0.f) {
            float iz = 1.f / (cz + EPSF);
            float x = cx * iz - 0.5f;
            float y = cy * iz - 0.5f;
            float x0f = floorf(x), y0f = floorf(y);
            float fx = x - x0f, fy = y - y0f;
            float x1f = x0f + 1.f, y1f = y0f + 1.f;
            int ix0 = (int)fminf(fmaxf(x0f, 0.f), (float)(WW - 1));
            int ix1 = (int)fminf(fmaxf(x1f, 0.f), (float)(WW - 1));
            int iy0 = (int)fminf(fmaxf(y0f, 0.f), (float)(HH - 1));
            int iy1 = (int)fminf(fmaxf(y1f, 0.f), (float)(HH - 1));
            bool vx0 = (x0f >= 0.f) && (x0f < (float)WW);
            bool vx1 = (x1f >= 0.f) && (x1f < (float)WW);
            bool vy0 = (y0f >= 0.f) && (y0f < (float)HH);
            bool vy1 = (y1f >= 0.f) && (y1f < (float)HH);
            float w00 = (vx0 && vy0) ? (1.f - fx) * (1.f - fy) : 0.f;
            float w01 = (vx1 && vy0) ? fx * (1.f - fy) : 0.f;
            float w10 = (vx0 && vy1) ? (1.f - fx) * fy : 0.f;
            float w11 = (vx1 && vy1) ? fx * fy : 0.f;

            float d00 = 0.f, d01 = 0.f, d10 = 0.f, d11 = 0.f;
            int b = v * CC * HW;
            int i00 = iy0 * WW + ix0, i01 = iy0 * WW + ix1;
            int i10 = iy1 * WW + ix0, i11 = iy1 * WW + ix1;
            #pragma unroll
            for (int c = 0; c < CC; ++c) {
                const float* fc = srcF + b + c * HW;
                d00 += fc[i00] * cf[c];
                d01 += fc[i01] * cf[c];
                d10 += fc[i10] * cf[c];
                d11 += fc[i11] * cf[c];
            }
            acc += w00 * d00 + w01 * d01 + w10 * d10 + w11 * d11;
        }
    }
    out[tid] = acc;
}

extern "C" void kernel_launch(void* const* d_in, const int* in_sizes, int n_in,
                              void* d_out, int out_size, void* d_ws, size_t ws_size,
                              hipStream_t stream) {
    const float* cur  = (const float*)d_in[0];
    const float* src  = (const float*)d_in[1];
    const float* extr = (const float*)d_in[2];
    const float* Ks   = (const float*)d_in[3];
    const float* invK = (const float*)d_in[4];
    const float* mind = (const float*)d_in[5];
    const float* maxd = (const float*)d_in[6];
    float* out = (float*)d_out;

    const size_t need = (size_t)(VV * HW * CC + HW * CC) * sizeof(__half);
    const int n_out  = DD * HW;

    if (ws_size >= need) {
        __half* srcT = (__half*)d_ws;
        __half* curT = srcT + (size_t)VV * HW * CC;
        const int total = VV * HW + HW;
        cv_pack_kernel<<<(total + 255) / 256, 256, 0, stream>>>(src, cur, srcT, curT);
        const int mblocks = HW / PIX_PER_BLOCK;   // 1536
        cost_volume_f16_kernel<<<mblocks, 256, 0, stream>>>(
            curT, srcT, extr, Ks, invK, mind, maxd, out);
    } else {
        const int blocks = (n_out + 255) / 256;
        cost_volume_fallback_kernel<<<blocks, 256, 0, stream>>>(
            cur, src, extr, Ks, invK, mind, maxd, out);
    }
}

// Round 3
// 79.013 us; speedup vs baseline: 1.0356x; 1.0013x over previous
//
#include <hip/hip_runtime.h>
#include <hip/hip_fp16.h>

#define HH 64
#define WW 96
#define DD 64
#define VV 4
#define CC 16
#define HW (HH*WW)
#define EPSF 1e-8f

typedef _Float16 half2_t __attribute__((ext_vector_type(2)));

#if defined(__has_builtin)
#if __has_builtin(__builtin_amdgcn_fdot2)
#define HAVE_FDOT2 1
#endif
#endif

__device__ __forceinline__ float fdot2_acc(half2_t a, half2_t b, float c) {
#ifdef HAVE_FDOT2
    return __builtin_amdgcn_fdot2(a, b, c, false);
#else
    return c + (float)a.x * (float)b.x + (float)a.y * (float)b.y;
#endif
}

// ---------------------------------------------------------------------------
// Pack kernel: src (V,C,HW) fp32 -> srcT (V,HW,C) fp16
//              cur (C,HW)  fp32 -> curT (HW,C)   fp16
// One thread per pixel: channel reads coalesced across lanes, 32B packed write.
// ---------------------------------------------------------------------------
__global__ __launch_bounds__(256) void cv_pack_kernel(
    const float* __restrict__ src, const float* __restrict__ cur,
    __half* __restrict__ srcT, __half* __restrict__ curT)
{
    int tid = blockIdx.x * blockDim.x + threadIdx.x;
    if (tid < VV * HW) {
        int v  = tid / HW;
        int hw = tid - v * HW;
        unsigned short pk[CC];
        #pragma unroll
        for (int c = 0; c < CC; ++c) {
            float f = src[(size_t)v * CC * HW + c * HW + hw];
            pk[c] = __half_as_ushort(__float2half(f));
        }
        uint4* dst = (uint4*)(srcT + (size_t)tid * CC);
        dst[0] = *(uint4*)&pk[0];
        dst[1] = *(uint4*)&pk[8];
    } else {
        int hw = tid - VV * HW;
        if (hw < HW) {
            unsigned short pk[CC];
            #pragma unroll
            for (int c = 0; c < CC; ++c) {
                float f = cur[c * HW + hw];
                pk[c] = __half_as_ushort(__float2half(f));
            }
            uint4* dst = (uint4*)(curT + (size_t)hw * CC);
            dst[0] = *(uint4*)&pk[0];
            dst[1] = *(uint4*)&pk[8];
        }
    }
}

// 16B fp16 tap (8 channels): 4 x v_dot2_f32_f16, fp32 accumulate
__device__ __forceinline__ float tap_dot8(const __half* __restrict__ p,
                                          const half2_t* __restrict__ cf2)
{
    half2_t hv[4];
    *(uint4*)&hv[0] = *(const uint4*)p;
    float s = 0.f;
    #pragma unroll
    for (int i = 0; i < 4; ++i)
        s = fdot2_acc(hv[i], cf2[i], s);
    return s;
}

// ---------------------------------------------------------------------------
// Main fused kernel, v4: round-0 mapping + channel-split thread pairs.
//  - Lane pair (2i,2i+1) = ONE output (d,hw); even lane reads channels 0..7
//    (bytes 0..15 of the 32B record), odd lane channels 8..15 (bytes 16..31).
//  - Each tap: ONE dwordx4/lane; 4 consecutive lanes fill one 64B line ->
//    ~16 distinct fully-utilized lines per wave-load (vs 32 half-used before).
//    Total tap line transactions halved.
//  - Bilinear weights are linear over the channel sum, so the pair merges
//    with a single __shfl_xor(acc,1) at the end; even lane stores.
//  - Projection math duplicated within the pair (VALU is not the bottleneck;
//    round-1 evidence). Divides -> v_rcp_f32 (passed twice, same absmax).
//  - 786432 threads / 3072 blocks: MORE latency hiding than the 76us baseline.
// ---------------------------------------------------------------------------
__global__ __launch_bounds__(256) void cost_volume_f16_kernel(
    const __half* __restrict__ curT,
    const __half* __restrict__ srcT,
    const float* __restrict__ extr,   // (V,4,4)
    const float* __restrict__ Ks,     // (V,4,4)
    const float* __restrict__ invK,   // (4,4)
    const float* __restrict__ min_d,
    const float* __restrict__ max_d,
    float* __restrict__ out)          // (D,HW)
{
    __shared__ float P_s[VV * 12];
    {
        int t = threadIdx.x;
        if (t < VV * 12) {
            int v   = t / 12;
            int r   = (t % 12) / 4;
            int col = t % 4;
            float s = 0.f;
            #pragma unroll
            for (int k = 0; k < 4; ++k)
                s += Ks[v * 16 + r * 4 + k] * extr[v * 16 + k * 4 + col];
            P_s[t] = s;
        }
    }
    __syncthreads();

    const int tid2    = blockIdx.x * blockDim.x + threadIdx.x;
    const int out_idx = tid2 >> 1;          // (d,hw) output element
    const int half    = tid2 & 1;           // channel half: 0 -> c0..7, 1 -> c8..15
    const int d  = out_idx / HW;
    const int hw = out_idx - d * HW;
    const int h  = hw / WW;
    const int w  = hw - h * WW;

    float px = (float)w + 0.5f, py = (float)h + 0.5f;
    float rx = invK[0] * px + invK[1] * py + invK[2];
    float ry = invK[4] * px + invK[5] * py + invK[6];
    float rz = invK[8] * px + invK[9] * py + invK[10];

    float inv_min = __builtin_amdgcn_rcpf(min_d[0]);
    float inv_max = __builtin_amdgcn_rcpf(max_d[0]);
    float depth = __builtin_amdgcn_rcpf(
        inv_min + (inv_max - inv_min) * ((float)d * (1.f / (float)(DD - 1))));

    // this thread's 8-channel slice of the current-pixel feature vector
    half2_t cf2[4];
    {
        const uint4* p = (const uint4*)(curT + (size_t)hw * CC + half * 8);
        *(uint4*)&cf2[0] = *p;
    }

    float acc = 0.f;
    #pragma unroll
    for (int v = 0; v < VV; ++v) {
        const float* P = &P_s[v * 12];
        float cx = depth * (P[0] * rx + P[1] * ry + P[2]  * rz) + P[3];
        float cy = depth * (P[4] * rx + P[5] * ry + P[6]  * rz) + P[7];
        float cz = depth * (P[8] * rx + P[9] * ry + P[10] * rz) + P[11];
        if (cz > 0.f) {
            float iz = __builtin_amdgcn_rcpf(cz + EPSF);
            float x = cx * iz - 0.5f;
            float y = cy * iz - 0.5f;
            float x0f = floorf(x), y0f = floorf(y);
            float fx = x - x0f, fy = y - y0f;
            float x1f = x0f + 1.f, y1f = y0f + 1.f;
            int ix0 = (int)fminf(fmaxf(x0f, 0.f), (float)(WW - 1));
            int ix1 = (int)fminf(fmaxf(x1f, 0.f), (float)(WW - 1));
            int iy0 = (int)fminf(fmaxf(y0f, 0.f), (float)(HH - 1));
            int iy1 = (int)fminf(fmaxf(y1f, 0.f), (float)(HH - 1));
            bool vx0 = (x0f >= 0.f) && (x0f < (float)WW);
            bool vx1 = (x1f >= 0.f) && (x1f < (float)WW);
            bool vy0 = (y0f >= 0.f) && (y0f < (float)HH);
            bool vy1 = (y1f >= 0.f) && (y1f < (float)HH);
            float w00 = (vx0 && vy0) ? (1.f - fx) * (1.f - fy) : 0.f;
            float w01 = (vx1 && vy0) ? fx * (1.f - fy) : 0.f;
            float w10 = (vx0 && vy1) ? (1.f - fx) * fy : 0.f;
            float w11 = (vx1 && vy1) ? fx * fy : 0.f;

            // byte offset = record*32 + half*16 -> one dwordx4 per tap
            const __half* base = srcT + (size_t)v * HW * CC + half * 8;
            float d00 = tap_dot8(base + (size_t)(iy0 * WW + ix0) * CC, cf2);
            float d01 = tap_dot8(base + (size_t)(iy0 * WW + ix1) * CC, cf2);
            float d10 = tap_dot8(base + (size_t)(iy1 * WW + ix0) * CC, cf2);
            float d11 = tap_dot8(base + (size_t)(iy1 * WW + ix1) * CC, cf2);

            acc += w00 * d00 + w01 * d01 + w10 * d10 + w11 * d11;
        }
    }

    // merge the two channel halves of this output
    acc += __shfl_xor(acc, 1, 64);
    if (half == 0)
        out[out_idx] = acc;
}

// ---------------------------------------------------------------------------
// Fallback (no workspace): original-layout fp32 gather.
// ---------------------------------------------------------------------------
__global__ __launch_bounds__(256) void cost_volume_fallback_kernel(
    const float* __restrict__ curF,   // (C,HW)
    const float* __restrict__ srcF,   // (V,C,HW)
    const float* __restrict__ extr,
    const float* __restrict__ Ks,
    const float* __restrict__ invK,
    const float* __restrict__ min_d,
    const float* __restrict__ max_d,
    float* __restrict__ out)
{
    __shared__ float P_s[VV * 12];
    {
        int t = threadIdx.x;
        if (t < VV * 12) {
            int v   = t / 12;
            int r   = (t % 12) / 4;
            int col = t % 4;
            float s = 0.f;
            #pragma unroll
            for (int k = 0; k < 4; ++k)
                s += Ks[v * 16 + r * 4 + k] * extr[v * 16 + k * 4 + col];
            P_s[t] = s;
        }
    }
    __syncthreads();

    int tid = blockIdx.x * blockDim.x + threadIdx.x;
    if (tid >= DD * HW) return;
    int d  = tid / HW;
    int hw = tid - d * HW;
    int h  = hw / WW;
    int w  = hw - h * WW;

    float px = (float)w + 0.5f, py = (float)h + 0.5f;
    float rx = invK[0] * px + invK[1] * py + invK[2];
    float ry = invK[4] * px + invK[5] * py + invK[6];
    float rz = invK[8] * px + invK[9] * py + invK[10];

    float inv_min = 1.f / min_d[0];
    float inv_max = 1.f / max_d[0];
    float depth   = 1.f / (inv_min + (inv_max - inv_min) * ((float)d / (float)(DD - 1)));

    float cf[CC];
    #pragma unroll
    for (int c = 0; c < CC; ++c) cf[c] = curF[c * HW + hw];

    float acc = 0.f;
    #pragma unroll
    for (int v = 0; v < VV; ++v) {
        const float* P = &P_s[v * 12];
        float cx = depth * (P[0] * rx + P[1] * ry + P[2]  * rz) + P[3];
        float cy = depth * (P[4] * rx + P[5] * ry + P[6]  * rz) + P[7];
        float cz = depth * (P[8] * rx + P[9] * ry + P[10] * rz) + P[11];
        if (cz > 0.f) {
            float iz = 1.f / (cz + EPSF);
            float x = cx * iz - 0.5f;
            float y = cy * iz - 0.5f;
            float x0f = floorf(x), y0f = floorf(y);
            float fx = x - x0f, fy = y - y0f;
            float x1f = x0f + 1.f, y1f = y0f + 1.f;
            int ix0 = (int)fminf(fmaxf(x0f, 0.f), (float)(WW - 1));
            int ix1 = (int)fminf(fmaxf(x1f, 0.f), (float)(WW - 1));
            int iy0 = (int)fminf(fmaxf(y0f, 0.f), (float)(HH - 1));
            int iy1 = (int)fminf(fmaxf(y1f, 0.f), (float)(HH - 1));
            bool vx0 = (x0f >= 0.f) && (x0f < (float)WW);
            bool vx1 = (x1f >= 0.f) && (x1f < (float)WW);
            bool vy0 = (y0f >= 0.f) && (y0f < (float)HH);
            bool vy1 = (y1f >= 0.f) && (y1f < (float)HH);
            float w00 = (vx0 && vy0) ? (1.f - fx) * (1.f - fy) : 0.f;
            float w01 = (vx1 && vy0) ? fx * (1.f - fy) : 0.f;
            float w10 = (vx0 && vy1) ? (1.f - fx) * fy : 0.f;
            float w11 = (vx1 && vy1) ? fx * fy : 0.f;

            float d00 = 0.f, d01 = 0.f, d10 = 0.f, d11 = 0.f;
            int b = v * CC * HW;
            int i00 = iy0 * WW + ix0, i01 = iy0 * WW + ix1;
            int i10 = iy1 * WW + ix0, i11 = iy1 * WW + ix1;
            #pragma unroll
            for (int c = 0; c < CC; ++c) {
                const float* fc = srcF + b + c * HW;
                d00 += fc[i00] * cf[c];
                d01 += fc[i01] * cf[c];
                d10 += fc[i10] * cf[c];
                d11 += fc[i11] * cf[c];
            }
            acc += w00 * d00 + w01 * d01 + w10 * d10 + w11 * d11;
        }
    }
    out[tid] = acc;
}

extern "C" void kernel_launch(void* const* d_in, const int* in_sizes, int n_in,
                              void* d_out, int out_size, void* d_ws, size_t ws_size,
                              hipStream_t stream) {
    const float* cur  = (const float*)d_in[0];
    const float* src  = (const float*)d_in[1];
    const float* extr = (const float*)d_in[2];
    const float* Ks   = (const float*)d_in[3];
    const float* invK = (const float*)d_in[4];
    const float* mind = (const float*)d_in[5];
    const float* maxd = (const float*)d_in[6];
    float* out = (float*)d_out;

    const size_t need = (size_t)(VV * HW * CC + HW * CC) * sizeof(__half);
    const int n_out  = DD * HW;

    if (ws_size >= need) {
        __half* srcT = (__half*)d_ws;
        __half* curT = srcT + (size_t)VV * HW * CC;
        const int total = VV * HW + HW;
        cv_pack_kernel<<<(total + 255) / 256, 256, 0, stream>>>(src, cur, srcT, curT);
        const int mblocks = (DD * HW * 2) / 256;   // 3072: 2 threads per output
        cost_volume_f16_kernel<<<mblocks, 256, 0, stream>>>(
            curT, srcT, extr, Ks, invK, mind, maxd, out);
    } else {
        const int blocks = (n_out + 255) / 256;
        cost_volume_fallback_kernel<<<blocks, 256, 0, stream>>>(
            cur, src, extr, Ks, invK, mind, maxd, out);
    }
}

// Round 4
// 75.360 us; speedup vs baseline: 1.0858x; 1.0485x over previous
//
#include <hip/hip_runtime.h>
#include <hip/hip_fp16.h>

#define HH 64
#define WW 96
#define DD 64
#define VV 4
#define CC 16
#define HW (HH*WW)
#define EPSF 1e-8f

typedef _Float16 half2_t __attribute__((ext_vector_type(2)));

#if defined(__has_builtin)
#if __has_builtin(__builtin_amdgcn_fdot2)
#define HAVE_FDOT2 1
#endif
#endif

__device__ __forceinline__ float fdot2_acc(half2_t a, half2_t b, float c) {
#ifdef HAVE_FDOT2
    return __builtin_amdgcn_fdot2(a, b, c, false);
#else
    return c + (float)a.x * (float)b.x + (float)a.y * (float)b.y;
#endif
}

// ---------------------------------------------------------------------------
// Pack kernel: src (V,C,HW) fp32 -> srcT (V,HW,C) fp16
//              cur (C,HW)  fp32 -> curT (HW,C)   fp16
// One thread per pixel: channel reads coalesced across lanes, 32B packed write.
// ---------------------------------------------------------------------------
__global__ __launch_bounds__(256) void cv_pack_kernel(
    const float* __restrict__ src, const float* __restrict__ cur,
    __half* __restrict__ srcT, __half* __restrict__ curT)
{
    int tid = blockIdx.x * blockDim.x + threadIdx.x;
    if (tid < VV * HW) {
        int v  = tid / HW;
        int hw = tid - v * HW;
        unsigned short pk[CC];
        #pragma unroll
        for (int c = 0; c < CC; ++c) {
            float f = src[(size_t)v * CC * HW + c * HW + hw];
            pk[c] = __half_as_ushort(__float2half(f));
        }
        uint4* dst = (uint4*)(srcT + (size_t)tid * CC);
        dst[0] = *(uint4*)&pk[0];
        dst[1] = *(uint4*)&pk[8];
    } else {
        int hw = tid - VV * HW;
        if (hw < HW) {
            unsigned short pk[CC];
            #pragma unroll
            for (int c = 0; c < CC; ++c) {
                float f = cur[c * HW + hw];
                pk[c] = __half_as_ushort(__float2half(f));
            }
            uint4* dst = (uint4*)(curT + (size_t)hw * CC);
            dst[0] = *(uint4*)&pk[0];
            dst[1] = *(uint4*)&pk[8];
        }
    }
}

// 32B fp16 tap: 8 x v_dot2_f32_f16 against fp16 cf, fp32 accumulate
__device__ __forceinline__ float tap_dot16(const __half* __restrict__ p,
                                           const half2_t* __restrict__ cf2)
{
    half2_t hv[8];
    const uint4* q = (const uint4*)p;
    *(uint4*)&hv[0] = q[0];
    *(uint4*)&hv[4] = q[1];
    float s = 0.f;
    #pragma unroll
    for (int i = 0; i < 8; ++i)
        s = fdot2_acc(hv[i], cf2[i], s);
    return s;
}

// ---------------------------------------------------------------------------
// Main fused kernel, v5: round-0 structure (measured best, 76.0us) with the
// only strictly-work-reducing change: all divides -> v_rcp_f32 (verified at
// identical absmax across rounds 1-3). One thread per output (d,h,w).
//  - Round-1 lesson: the 6144-wave pool is load-bearing (latency hiding);
//    do NOT amortize across depths at the cost of occupancy.
//  - Rounds 2-3 lesson: tap line-traffic tuning is worth < noise (~2us);
//    keep the simplest mapping.
// ---------------------------------------------------------------------------
__global__ __launch_bounds__(256) void cost_volume_f16_kernel(
    const __half* __restrict__ curT,
    const __half* __restrict__ srcT,
    const float* __restrict__ extr,   // (V,4,4)
    const float* __restrict__ Ks,     // (V,4,4)
    const float* __restrict__ invK,   // (4,4)
    const float* __restrict__ min_d,
    const float* __restrict__ max_d,
    float* __restrict__ out)          // (D,HW)
{
    __shared__ float P_s[VV * 12];
    {
        int t = threadIdx.x;
        if (t < VV * 12) {
            int v   = t / 12;
            int r   = (t % 12) / 4;
            int col = t % 4;
            float s = 0.f;
            #pragma unroll
            for (int k = 0; k < 4; ++k)
                s += Ks[v * 16 + r * 4 + k] * extr[v * 16 + k * 4 + col];
            P_s[t] = s;
        }
    }
    __syncthreads();

    int tid = blockIdx.x * blockDim.x + threadIdx.x;
    if (tid >= DD * HW) return;
    int d  = tid / HW;
    int hw = tid - d * HW;
    int h  = hw / WW;
    int w  = hw - h * WW;

    float px = (float)w + 0.5f, py = (float)h + 0.5f;
    float rx = invK[0] * px + invK[1] * py + invK[2];
    float ry = invK[4] * px + invK[5] * py + invK[6];
    float rz = invK[8] * px + invK[9] * py + invK[10];

    float inv_min = __builtin_amdgcn_rcpf(min_d[0]);
    float inv_max = __builtin_amdgcn_rcpf(max_d[0]);
    float depth   = __builtin_amdgcn_rcpf(
        inv_min + (inv_max - inv_min) * ((float)d * (1.f / (float)(DD - 1))));

    half2_t cf2[8];
    {
        const uint4* p = (const uint4*)(curT + (size_t)hw * CC);
        *(uint4*)&cf2[0] = p[0];
        *(uint4*)&cf2[4] = p[1];
    }

    float acc = 0.f;
    #pragma unroll
    for (int v = 0; v < VV; ++v) {
        const float* P = &P_s[v * 12];
        float cx = depth * (P[0] * rx + P[1] * ry + P[2]  * rz) + P[3];
        float cy = depth * (P[4] * rx + P[5] * ry + P[6]  * rz) + P[7];
        float cz = depth * (P[8] * rx + P[9] * ry + P[10] * rz) + P[11];
        if (cz > 0.f) {
            float iz = __builtin_amdgcn_rcpf(cz + EPSF);
            float x = cx * iz - 0.5f;
            float y = cy * iz - 0.5f;
            float x0f = floorf(x), y0f = floorf(y);
            float fx = x - x0f, fy = y - y0f;
            float x1f = x0f + 1.f, y1f = y0f + 1.f;
            int ix0 = (int)fminf(fmaxf(x0f, 0.f), (float)(WW - 1));
            int ix1 = (int)fminf(fmaxf(x1f, 0.f), (float)(WW - 1));
            int iy0 = (int)fminf(fmaxf(y0f, 0.f), (float)(HH - 1));
            int iy1 = (int)fminf(fmaxf(y1f, 0.f), (float)(HH - 1));
            bool vx0 = (x0f >= 0.f) && (x0f < (float)WW);
            bool vx1 = (x1f >= 0.f) && (x1f < (float)WW);
            bool vy0 = (y0f >= 0.f) && (y0f < (float)HH);
            bool vy1 = (y1f >= 0.f) && (y1f < (float)HH);
            float w00 = (vx0 && vy0) ? (1.f - fx) * (1.f - fy) : 0.f;
            float w01 = (vx1 && vy0) ? fx * (1.f - fy) : 0.f;
            float w10 = (vx0 && vy1) ? (1.f - fx) * fy : 0.f;
            float w11 = (vx1 && vy1) ? fx * fy : 0.f;

            const __half* base = srcT + (size_t)v * HW * CC;
            float d00 = tap_dot16(base + (size_t)(iy0 * WW + ix0) * CC, cf2);
            float d01 = tap_dot16(base + (size_t)(iy0 * WW + ix1) * CC, cf2);
            float d10 = tap_dot16(base + (size_t)(iy1 * WW + ix0) * CC, cf2);
            float d11 = tap_dot16(base + (size_t)(iy1 * WW + ix1) * CC, cf2);

            acc += w00 * d00 + w01 * d01 + w10 * d10 + w11 * d11;
        }
    }
    out[tid] = acc;
}

// ---------------------------------------------------------------------------
// Fallback (no workspace): original-layout fp32 gather.
// ---------------------------------------------------------------------------
__global__ __launch_bounds__(256) void cost_volume_fallback_kernel(
    const float* __restrict__ curF,   // (C,HW)
    const float* __restrict__ srcF,   // (V,C,HW)
    const float* __restrict__ extr,
    const float* __restrict__ Ks,
    const float* __restrict__ invK,
    const float* __restrict__ min_d,
    const float* __restrict__ max_d,
    float* __restrict__ out)
{
    __shared__ float P_s[VV * 12];
    {
        int t = threadIdx.x;
        if (t < VV * 12) {
            int v   = t / 12;
            int r   = (t % 12) / 4;
            int col = t % 4;
            float s = 0.f;
            #pragma unroll
            for (int k = 0; k < 4; ++k)
                s += Ks[v * 16 + r * 4 + k] * extr[v * 16 + k * 4 + col];
            P_s[t] = s;
        }
    }
    __syncthreads();

    int tid = blockIdx.x * blockDim.x + threadIdx.x;
    if (tid >= DD * HW) return;
    int d  = tid / HW;
    int hw = tid - d * HW;
    int h  = hw / WW;
    int w  = hw - h * WW;

    float px = (float)w + 0.5f, py = (float)h + 0.5f;
    float rx = invK[0] * px + invK[1] * py + invK[2];
    float ry = invK[4] * px + invK[5] * py + invK[6];
    float rz = invK[8] * px + invK[9] * py + invK[10];

    float inv_min = 1.f / min_d[0];
    float inv_max = 1.f / max_d[0];
    float depth   = 1.f / (inv_min + (inv_max - inv_min) * ((float)d / (float)(DD - 1)));

    float cf[CC];
    #pragma unroll
    for (int c = 0; c < CC; ++c) cf[c] = curF[c * HW + hw];

    float acc = 0.f;
    #pragma unroll
    for (int v = 0; v < VV; ++v) {
        const float* P = &P_s[v * 12];
        float cx = depth * (P[0] * rx + P[1] * ry + P[2]  * rz) + P[3];
        float cy = depth * (P[4] * rx + P[5] * ry + P[6]  * rz) + P[7];
        float cz = depth * (P[8] * rx + P[9] * ry + P[10] * rz) + P[11];
        if (cz > 0.f) {
            float iz = 1.f / (cz + EPSF);
            float x = cx * iz - 0.5f;
            float y = cy * iz - 0.5f;
            float x0f = floorf(x), y0f = floorf(y);
            float fx = x - x0f, fy = y - y0f;
            float x1f = x0f + 1.f, y1f = y0f + 1.f;
            int ix0 = (int)fminf(fmaxf(x0f, 0.f), (float)(WW - 1));
            int ix1 = (int)fminf(fmaxf(x1f, 0.f), (float)(WW - 1));
            int iy0 = (int)fminf(fmaxf(y0f, 0.f), (float)(HH - 1));
            int iy1 = (int)fminf(fmaxf(y1f, 0.f), (float)(HH - 1));
            bool vx0 = (x0f >= 0.f) && (x0f < (float)WW);
            bool vx1 = (x1f >= 0.f) && (x1f < (float)WW);
            bool vy0 = (y0f >= 0.f) && (y0f < (float)HH);
            bool vy1 = (y1f >= 0.f) && (y1f < (float)HH);
            float w00 = (vx0 && vy0) ? (1.f - fx) * (1.f - fy) : 0.f;
            float w01 = (vx1 && vy0) ? fx * (1.f - fy) : 0.f;
            float w10 = (vx0 && vy1) ? (1.f - fx) * fy : 0.f;
            float w11 = (vx1 && vy1) ? fx * fy : 0.f;

            float d00 = 0.f, d01 = 0.f, d10 = 0.f, d11 = 0.f;
            int b = v * CC * HW;
            int i00 = iy0 * WW + ix0, i01 = iy0 * WW + ix1;
            int i10 = iy1 * WW + ix0, i11 = iy1 * WW + ix1;
            #pragma unroll
            for (int c = 0; c < CC; ++c) {
                const float* fc = srcF + b + c * HW;
                d00 += fc[i00] * cf[c];
                d01 += fc[i01] * cf[c];
                d10 += fc[i10] * cf[c];
                d11 += fc[i11] * cf[c];
            }
            acc += w00 * d00 + w01 * d01 + w10 * d10 + w11 * d11;
        }
    }
    out[tid] = acc;
}

extern "C" void kernel_launch(void* const* d_in, const int* in_sizes, int n_in,
                              void* d_out, int out_size, void* d_ws, size_t ws_size,
                              hipStream_t stream) {
    const float* cur  = (const float*)d_in[0];
    const float* src  = (const float*)d_in[1];
    const float* extr = (const float*)d_in[2];
    const float* Ks   = (const float*)d_in[3];
    const float* invK = (const float*)d_in[4];
    const float* mind = (const float*)d_in[5];
    const float* maxd = (const float*)d_in[6];
    float* out = (float*)d_out;

    const size_t need = (size_t)(VV * HW * CC + HW * CC) * sizeof(__half);
    const int n_out  = DD * HW;
    const int blocks = (n_out + 255) / 256;

    if (ws_size >= need) {
        __half* srcT = (__half*)d_ws;
        __half* curT = srcT + (size_t)VV * HW * CC;
        const int total = VV * HW + HW;
        cv_pack_kernel<<<(total + 255) / 256, 256, 0, stream>>>(src, cur, srcT, curT);
        cost_volume_f16_kernel<<<blocks, 256, 0, stream>>>(
            curT, srcT, extr, Ks, invK, mind, maxd, out);
    } else {
        cost_volume_fallback_kernel<<<blocks, 256, 0, stream>>>(
            cur, src, extr, Ks, invK, mind, maxd, out);
    }
}